// Round 11
// baseline (276.702 us; speedup 1.0000x reference)
//
#include <hip/hip_runtime.h>

#define N_NODES  100000
#define N_EDGES  1600000
#define IN_CH    128
#define HID      32
#define N_GRAPHS 64

#define NBIN   391            // bins of 256 dst nodes: bin = dst >> 8
#define CHUNK  4096           // edges per multisplit block
#define MGRID  391            // ceil(1.6M / 4096)
#define STG    5120           // csr2 per-bin staging capacity

// workspace layout (4-byte element offsets) — ~26.4 MB (ws is 256 MiB per fill evidence)
#define OFF_B1     0          // uint[1.6M] bf16-packed layer-1 features; H aliases head (dead before gemm1)
#define OFF_B2     1600000    // uint[1.6M] bf16-packed layer-2 features
#define OFF_EDGEPK 3200000    // int[1.6M]
#define OFF_CSR    4800000    // int[1.6M]
#define OFF_COLT   6400000    // int[391]
#define OFF_BINB   6400391    // int[392]
#define OFF_ROWPTR 6400784    // int[100,001]
#define OFF_DINV   6500785    // float[100,000]
#define OFF_GSUM   6600785    // float[2048]
#define OFF_CNT    6602833    // float[64]

// bf16 pack (RNE) / unpack helpers
__device__ __forceinline__ unsigned bfr(float f) {
    unsigned u = __float_as_uint(f);
    u += 0x7fffu + ((u >> 16) & 1u);
    return u >> 16;
}
__device__ __forceinline__ float bflo(unsigned w) { return __uint_as_float(w << 16); }
__device__ __forceinline__ float bfhi(unsigned w) { return __uint_as_float(w & 0xffff0000u); }

// ---------- phase 1: per-(bin, wg) histogram ----------
__global__ __launch_bounds__(512) void hist_kernel(const int* __restrict__ dst,
                                                   int* __restrict__ H) {
    __shared__ int s[512];
    int t = threadIdx.x, wg = blockIdx.x;
    s[t] = 0;
    __syncthreads();
    int e0 = wg * CHUNK, e1 = min(e0 + CHUNK, N_EDGES);
    for (int e = e0 + t; e < e1; e += 512) {
        int d = dst[e];
        if ((unsigned)d < N_NODES) atomicAdd(&s[d >> 8], 1);
    }
    __syncthreads();
    if (t < NBIN) H[t * MGRID + wg] = s[t];
}

// ---------- phase 2a ----------
__global__ __launch_bounds__(512) void scanrow_kernel(int* __restrict__ H,
                                                      int* __restrict__ colT) {
    __shared__ int s[512];
    int t = threadIdx.x, bin = blockIdx.x;
    s[t] = (t < MGRID) ? H[bin * MGRID + t] : 0;
    __syncthreads();
    for (int off = 1; off < 512; off <<= 1) {
        int v = (t >= off) ? s[t - off] : 0;
        __syncthreads();
        if (t >= off) s[t] += v;
        __syncthreads();
    }
    if (t < MGRID) H[bin * MGRID + t] = t ? s[t - 1] : 0;
    if (t == 0) colT[bin] = s[MGRID - 1];
}

// ---------- phase 2b ----------
__global__ __launch_bounds__(512) void scanbase_kernel(const int* __restrict__ colT,
                                                       int* __restrict__ binB,
                                                       int* __restrict__ row_ptr) {
    __shared__ int s[512];
    int t = threadIdx.x;
    s[t] = (t < NBIN) ? colT[t] : 0;
    __syncthreads();
    for (int off = 1; off < 512; off <<= 1) {
        int v = (t >= off) ? s[t - off] : 0;
        __syncthreads();
        if (t >= off) s[t] += v;
        __syncthreads();
    }
    if (t < NBIN) binB[t] = t ? s[t - 1] : 0;
    if (t == 0) { binB[NBIN] = s[NBIN - 1]; row_ptr[N_NODES] = s[NBIN - 1]; }
}

// ---------- phase 3: bin-grouped scatter, LDS-staged coalesced flush ----------
__global__ __launch_bounds__(512) void msplit_kernel(const int* __restrict__ src,
                                                     const int* __restrict__ dst,
                                                     const int* __restrict__ H,
                                                     const int* __restrict__ binB,
                                                     int* __restrict__ edgepk) {
    __shared__ int s[512];
    __shared__ int cur[NBIN];
    __shared__ int gb[NBIN];
    __shared__ int stage[CHUNK];
    __shared__ int gof[CHUNK];
    int t = threadIdx.x, wg = blockIdx.x;
    s[t] = 0;
    __syncthreads();
    int e0 = wg * CHUNK, e1 = min(e0 + CHUNK, N_EDGES);
    for (int e = e0 + t; e < e1; e += 512) {
        int d = dst[e];
        if ((unsigned)d < N_NODES) atomicAdd(&s[d >> 8], 1);
    }
    __syncthreads();
    for (int off = 1; off < 512; off <<= 1) {
        int v = (t >= off) ? s[t - off] : 0;
        __syncthreads();
        if (t >= off) s[t] += v;
        __syncthreads();
    }
    if (t < NBIN) {
        int lo = t ? s[t - 1] : 0;
        cur[t] = lo;
        gb[t] = binB[t] + H[t * MGRID + wg] - lo;
    }
    __syncthreads();
    for (int e = e0 + t; e < e1; e += 512) {
        int d = dst[e];
        if ((unsigned)d < N_NODES) {
            int b = d >> 8;
            int p = atomicAdd(&cur[b], 1);
            stage[p] = (src[e] << 8) | (d & 255);
            gof[p] = gb[b];
        }
    }
    __syncthreads();
    int total = s[511];
    for (int p = t; p < total; p += 512)
        edgepk[gof[p] + p] = stage[p];
}

// ---------- phase 4: within-bin reorder -> CSR + dinv/row_ptr ----------
__global__ __launch_bounds__(256) void csr2_kernel(const int* __restrict__ edgepk,
                                                   const int* __restrict__ binB,
                                                   int* __restrict__ row_ptr,
                                                   float* __restrict__ dinv,
                                                   int* __restrict__ csr) {
    __shared__ int cnt[256], s[256], cur[256];
    __shared__ int stage[STG];
    int t = threadIdx.x, bin = blockIdx.x;
    int ebase = binB[bin], eend = binB[bin + 1];
    int n = eend - ebase;
    cnt[t] = 0;
    __syncthreads();
    for (int p = ebase + t; p < eend; p += 256)
        atomicAdd(&cnt[edgepk[p] & 255], 1);
    __syncthreads();
    s[t] = cnt[t];
    __syncthreads();
    for (int off = 1; off < 256; off <<= 1) {
        int v = (t >= off) ? s[t - off] : 0;
        __syncthreads();
        if (t >= off) s[t] += v;
        __syncthreads();
    }
    int excl = t ? s[t - 1] : 0;
    int node = (bin << 8) + t;
    if (node < N_NODES) {
        dinv[node] = rsqrtf((float)(cnt[t] + 1));
        row_ptr[node] = ebase + excl;
    }
    cur[t] = excl;
    __syncthreads();
    for (int p = ebase + t; p < eend; p += 256) {
        int w = edgepk[p];
        int l = atomicAdd(&cur[w & 255], 1);
        int sv = w >> 8;
        if (l < STG) stage[l] = sv;
        else csr[ebase + l] = sv;
    }
    __syncthreads();
    int lim = min(n, STG);
    for (int l = t; l < lim; l += 256)
        csr[ebase + l] = stage[l];
}

// ---------- Bu1(bf16) = (x @ W1) * dinv[row], register-tiled (4 ch/thread) ----------
#define XS1 132               // 128 + 4 pad
__global__ __launch_bounds__(256) void gemm1_kernel(const float* __restrict__ x,
                                                    const float* __restrict__ W1,
                                                    const float* __restrict__ dinv,
                                                    unsigned* __restrict__ Bu) {
    __shared__ float Wl[IN_CH * HID];   // 16 KB
    __shared__ float xs[32 * XS1];      // 16.9 KB
    int tid = threadIdx.x;
    for (int j = tid; j < IN_CH * HID / 4; j += 256)
        ((float4*)Wl)[j] = ((const float4*)W1)[j];
    int row0 = blockIdx.x * 32;         // 100000 % 32 == 0
    const float4* x4 = (const float4*)(x + (size_t)row0 * IN_CH);
    for (int j = tid; j < 32 * IN_CH / 4; j += 256) {
        int r = j >> 5, k4 = j & 31;
        ((float4*)&xs[r * XS1])[k4] = x4[j];
    }
    __syncthreads();
    int r = tid >> 3, cg = (tid & 7) * 4;
    const float* xr = &xs[r * XS1];
    float4 acc = {0.f, 0.f, 0.f, 0.f};
    #pragma unroll 8
    for (int k = 0; k < IN_CH; ++k) {
        float xv = xr[k];
        float4 w = *(const float4*)&Wl[k * HID + cg];
        acc.x += xv * w.x; acc.y += xv * w.y; acc.z += xv * w.z; acc.w += xv * w.w;
    }
    int row = row0 + r;
    float dv = dinv[row];
    uint2 p;
    p.x = bfr(acc.x * dv) | (bfr(acc.y * dv) << 16);
    p.y = bfr(acc.z * dv) | (bfr(acc.w * dv) << 16);
    *(uint2*)&Bu[(size_t)row * 16 + (tid & 7) * 2] = p;
}

// ---------- fused layer1 + gemm2: Bu2 = bf16( (relu(gather(Bu1)*dinv + b1) @ W2) * dinv ) ----------
// 512 threads = 16 nodes x 32 lanes (2 edge-parities x 16 ch-pairs)
#define XSP 33
__global__ __launch_bounds__(512) void l1g2_kernel(const unsigned* __restrict__ Bu1,
                                                   const int* __restrict__ csr,
                                                   const int* __restrict__ row_ptr,
                                                   const float* __restrict__ dinv,
                                                   const float* __restrict__ b1,
                                                   const float* __restrict__ W2,
                                                   unsigned* __restrict__ Bu2) {
    __shared__ float Wl[HID * HID];     // 4 KB
    __shared__ float xs[16 * XSP];      // 2.1 KB
    int tid = threadIdx.x;
    ((float2*)Wl)[tid] = ((const float2*)W2)[tid];   // 512 x float2 = 1024
    int r = tid >> 5, L = tid & 31, p = L >> 4, c2 = L & 15;
    int node = blockIdx.x * 16 + r;     // 100000 % 16 == 0
    unsigned wself = Bu1[(size_t)node * 16 + c2];
    float a0 = p ? 0.f : bflo(wself), a1 = p ? 0.f : bfhi(wself);
    int j = row_ptr[node], re = row_ptr[node + 1];
    for (; j + 8 <= re; j += 8) {       // 4 edges per parity per iter
        int s0 = csr[j + p], s1 = csr[j + 2 + p], s2 = csr[j + 4 + p], s3 = csr[j + 6 + p];
        unsigned w0 = Bu1[(size_t)s0 * 16 + c2], w1 = Bu1[(size_t)s1 * 16 + c2];
        unsigned w2 = Bu1[(size_t)s2 * 16 + c2], w3 = Bu1[(size_t)s3 * 16 + c2];
        a0 += (bflo(w0) + bflo(w1)) + (bflo(w2) + bflo(w3));
        a1 += (bfhi(w0) + bfhi(w1)) + (bfhi(w2) + bfhi(w3));
    }
    for (; j < re; j += 2) {
        int idx = j + p;
        if (idx < re) {
            unsigned w = Bu1[(size_t)csr[idx] * 16 + c2];
            a0 += bflo(w); a1 += bfhi(w);
        }
    }
    a0 += __shfl_xor(a0, 16);
    a1 += __shfl_xor(a1, 16);
    if (p == 0) {
        float dv = dinv[node];
        xs[r * XSP + 2 * c2]     = fmaxf(a0 * dv + b1[2 * c2], 0.f);
        xs[r * XSP + 2 * c2 + 1] = fmaxf(a1 * dv + b1[2 * c2 + 1], 0.f);
    }
    __syncthreads();
    // gemm2: 16 rows x 32 ch, 1 ch/thread
    int r2 = tid >> 5, c = tid & 31;
    const float* xr = &xs[r2 * XSP];
    float acc = 0.f;
    #pragma unroll
    for (int k = 0; k < HID; ++k) acc += xr[k] * Wl[k * HID + c];
    int row = blockIdx.x * 16 + r2;
    acc *= dinv[row];
    float o = __shfl_xor(acc, 1);       // partner channel
    if ((c & 1) == 0)
        Bu2[(size_t)row * 16 + (c >> 1)] = bfr(acc) | (bfr(o) << 16);
}

// ---------- fused layer2 + pool: out_h = gather(Bu2)*dinv + b2 ; gsum/cnt run-flush ----------
__global__ __launch_bounds__(512) void l2pool_kernel(const unsigned* __restrict__ Bu2,
                                                     const int* __restrict__ csr,
                                                     const int* __restrict__ row_ptr,
                                                     const float* __restrict__ dinv,
                                                     const float* __restrict__ b2,
                                                     const int* __restrict__ batch,
                                                     float* __restrict__ out_h,
                                                     float* __restrict__ gsum,
                                                     float* __restrict__ cnt) {
    __shared__ float xs[16 * XSP];
    __shared__ int bid[16];
    int tid = threadIdx.x;
    int r = tid >> 5, L = tid & 31, p = L >> 4, c2 = L & 15;
    int node = blockIdx.x * 16 + r;
    if (L == 0) bid[r] = batch[node];
    unsigned wself = Bu2[(size_t)node * 16 + c2];
    float a0 = p ? 0.f : bflo(wself), a1 = p ? 0.f : bfhi(wself);
    int j = row_ptr[node], re = row_ptr[node + 1];
    for (; j + 8 <= re; j += 8) {
        int s0 = csr[j + p], s1 = csr[j + 2 + p], s2 = csr[j + 4 + p], s3 = csr[j + 6 + p];
        unsigned w0 = Bu2[(size_t)s0 * 16 + c2], w1 = Bu2[(size_t)s1 * 16 + c2];
        unsigned w2 = Bu2[(size_t)s2 * 16 + c2], w3 = Bu2[(size_t)s3 * 16 + c2];
        a0 += (bflo(w0) + bflo(w1)) + (bflo(w2) + bflo(w3));
        a1 += (bfhi(w0) + bfhi(w1)) + (bfhi(w2) + bfhi(w3));
    }
    for (; j < re; j += 2) {
        int idx = j + p;
        if (idx < re) {
            unsigned w = Bu2[(size_t)csr[idx] * 16 + c2];
            a0 += bflo(w); a1 += bfhi(w);
        }
    }
    a0 += __shfl_xor(a0, 16);
    a1 += __shfl_xor(a1, 16);
    if (p == 0) {
        float dv = dinv[node];
        float2 o;
        o.x = a0 * dv + b2[2 * c2];
        o.y = a1 * dv + b2[2 * c2 + 1];
        *(float2*)&out_h[(size_t)node * HID + 2 * c2] = o;
        xs[r * XSP + 2 * c2] = o.x;
        xs[r * XSP + 2 * c2 + 1] = o.y;
    }
    __syncthreads();
    // pooling epilogue: 32 threads run-accumulate channels, thread 32 counts
    if (tid < 32) {
        float racc = 0.f; int rg = -1;
        for (int rr = 0; rr < 16; ++rr) {
            int g = bid[rr];
            float v = xs[rr * XSP + tid];
            if (g != rg) {
                if ((unsigned)rg < N_GRAPHS) atomicAdd(&gsum[rg * HID + tid], racc);
                rg = g; racc = v;
            } else racc += v;
        }
        if ((unsigned)rg < N_GRAPHS) atomicAdd(&gsum[rg * HID + tid], racc);
    } else if (tid == 32) {
        int rg = -1, rc = 0;
        for (int rr = 0; rr < 16; ++rr) {
            int g = bid[rr];
            if (g != rg) {
                if ((unsigned)rg < N_GRAPHS) atomicAdd(&cnt[rg], (float)rc);
                rg = g; rc = 1;
            } else ++rc;
        }
        if ((unsigned)rg < N_GRAPHS) atomicAdd(&cnt[rg], (float)rc);
    }
}

__global__ void summary_kernel(const float* __restrict__ gsum, const float* __restrict__ cnt,
                               const float* __restrict__ Ws, const float* __restrict__ bs,
                               float* __restrict__ out) {
    int g = blockIdx.x, c = threadIdx.x;
    float inv = 1.f / fmaxf(cnt[g], 1.f);
    float acc = bs[c];
    #pragma unroll
    for (int k = 0; k < HID; ++k)
        acc += gsum[g * HID + k] * inv * Ws[k * HID + c];
    out[g * HID + c] = acc;
}

extern "C" void kernel_launch(void* const* d_in, const int* in_sizes, int n_in,
                              void* d_out, int out_size, void* d_ws, size_t ws_size,
                              hipStream_t stream) {
    const float* x    = (const float*)d_in[0];
    const int* edge   = (const int*)d_in[1];
    const int* src    = edge;
    const int* dst    = edge + N_EDGES;
    const int* batch  = (const int*)d_in[2];
    const float* W1   = (const float*)d_in[3];
    const float* b1   = (const float*)d_in[4];
    const float* W2   = (const float*)d_in[5];
    const float* b2   = (const float*)d_in[6];
    const float* Ws   = (const float*)d_in[7];
    const float* bs   = (const float*)d_in[8];

    float* ws      = (float*)d_ws;
    unsigned* Bu1  = (unsigned*)(ws + OFF_B1);
    unsigned* Bu2  = (unsigned*)(ws + OFF_B2);
    int*   H       = (int*)(ws + OFF_B1);       // aliases Bu1; dead before gemm1
    int*   edgepk  = (int*)(ws + OFF_EDGEPK);
    int*   csr     = (int*)(ws + OFF_CSR);
    int*   colT    = (int*)(ws + OFF_COLT);
    int*   binB    = (int*)(ws + OFF_BINB);
    int*   row_ptr = (int*)(ws + OFF_ROWPTR);
    float* dinv    = ws + OFF_DINV;
    float* gsum    = ws + OFF_GSUM;
    float* cnt     = ws + OFF_CNT;

    float* out     = (float*)d_out;
    float* out_sum = out;
    float* out_h   = out + N_GRAPHS * HID;

    // CSR build
    hist_kernel    <<<MGRID, 512, 0, stream>>>(dst, H);
    scanrow_kernel <<<NBIN,  512, 0, stream>>>(H, colT);
    scanbase_kernel<<<1,     512, 0, stream>>>(colT, binB, row_ptr);
    msplit_kernel  <<<MGRID, 512, 0, stream>>>(src, dst, H, binB, edgepk);
    csr2_kernel    <<<NBIN,  256, 0, stream>>>(edgepk, binB, row_ptr, dinv, csr);

    hipMemsetAsync(gsum, 0, (N_GRAPHS * HID + N_GRAPHS) * sizeof(float), stream);

    // layers (fused)
    gemm1_kernel<<<N_NODES / 32, 256, 0, stream>>>(x, W1, dinv, Bu1);
    l1g2_kernel <<<N_NODES / 16, 512, 0, stream>>>(Bu1, csr, row_ptr, dinv, b1, W2, Bu2);
    l2pool_kernel<<<N_NODES / 16, 512, 0, stream>>>(Bu2, csr, row_ptr, dinv, b2, batch,
                                                    out_h, gsum, cnt);
    summary_kernel<<<N_GRAPHS, HID, 0, stream>>>(gsum, cnt, Ws, bs, out_sum);
}